// Round 1
// baseline (249.067 us; speedup 1.0000x reference)
//
#include <hip/hip_runtime.h>

// ---------------------------------------------------------------------------
// GalerkinAttention on MI355X (gfx950), bf16 MFMA pipeline.
//
// Shapes: B=4, N=8192, D=512, H=8, Dh=64, E3=1536, BN=32768 rows.
// Pipeline:
//   K0 : convert x, W_qkv, W_out to bf16
//   K1 : qkv = x @ W_qkv^T  (128x128 tile GEMM, m97 structure)
//        epilogue: q -> qb (row-major bf16); k,v -> per-head LayerNorm,
//        written TRANSPOSED knT/vnT [bh][64][8192] bf16 (so K2 reads rows)
//   K2 : P[bh] += Kn^T Vn   (MFMA from global, fp32 atomicAdd)
//   K2b: Pb = bf16(P / 8192)
//   K4a: out = q @ P per head (MFMA, LDS-staged)
//   K4b: y = out @ W_out^T + b_out (GEMM, fp32 store)
//
// MFMA conventions (16x16x32 bf16):
//   A frag: lane l holds A[row=l&15][k = ks*32 + (l>>4)*8 + e]   (e=0..7)
//   B frag: lane l holds B[k same][col=l&15]
//   (k-order is a bijection -> any consistent choice is correct)
//   C/D   : lane l reg r -> C[row=(l>>4)*4+r][col=l&15]  (m89-verified)
// ---------------------------------------------------------------------------

typedef __attribute__((ext_vector_type(8))) short bf16x8;
typedef __attribute__((ext_vector_type(4))) float f32x4;
typedef __attribute__((ext_vector_type(4))) unsigned short u16x4;

__device__ __forceinline__ unsigned short f2bf(float f) {
  unsigned int u = __builtin_bit_cast(unsigned int, f);
  u += 0x7FFFu + ((u >> 16) & 1u);   // RNE
  return (unsigned short)(u >> 16);
}

__device__ __forceinline__ f32x4 mfma16(bf16x8 a, bf16x8 b, f32x4 c) {
  return __builtin_amdgcn_mfma_f32_16x16x32_bf16(a, b, c, 0, 0, 0);
}

// async global->LDS, 16B per lane; lds ptr must be wave-uniform (HW adds lane*16)
__device__ __forceinline__ void gload16(const void* g, void* l) {
  __builtin_amdgcn_global_load_lds(
      (const __attribute__((address_space(1))) void*)g,
      (__attribute__((address_space(3))) void*)l, 16, 0, 0);
}

// ------------------------------- K0: convert -------------------------------
__global__ void k_cvt_bf16(const float* __restrict__ src,
                           unsigned short* __restrict__ dst, int n4) {
  int i = blockIdx.x * blockDim.x + threadIdx.x;
  if (i < n4) {
    float4 v = ((const float4*)src)[i];
    u16x4 o;
    o[0] = f2bf(v.x); o[1] = f2bf(v.y); o[2] = f2bf(v.z); o[3] = f2bf(v.w);
    ((u16x4*)dst)[i] = o;
  }
}

// ------------------------- K1: qkv GEMM + fused LN --------------------------
// grid (256 row-tiles, 12 col-tiles), 256 threads (4 waves, 2x2 quadrants)
__launch_bounds__(256)
__global__ void k1_qkv_ln(const unsigned short* __restrict__ xb,
                          const unsigned short* __restrict__ wqkvb,
                          const float* __restrict__ gK, const float* __restrict__ bK,
                          const float* __restrict__ gV, const float* __restrict__ bV,
                          unsigned short* __restrict__ qb,
                          unsigned short* __restrict__ knT,
                          unsigned short* __restrict__ vnT) {
  __shared__ __align__(16) unsigned short As[128 * 64];
  __shared__ __align__(16) unsigned short Bs[128 * 64];
  const int rt = blockIdx.x;
  const int ct = blockIdx.y;
  const int tid = (int)threadIdx.x;
  const int l = tid & 63;
  const int w = tid >> 6;
  const int wr = w >> 1, wc = w & 1;
  const int g = l >> 4, c16 = l & 15;
  const int row0 = rt * 128;
  const int col0 = ct * 128;

  // staging: wave w fills rows w*32..w*32+31 of the [128][64] bf16 tile
  const unsigned short* gsA = xb    + (row0 + w * 32 + (l >> 3)) * 512 + (l & 7) * 8;
  const unsigned short* gsB = wqkvb + (col0 + w * 32 + (l >> 3)) * 512 + (l & 7) * 8;

  f32x4 acc[4][4] = {};

  for (int kt = 0; kt < 8; ++kt) {
    const unsigned short* pa = gsA + kt * 64;
    const unsigned short* pb = gsB + kt * 64;
#pragma unroll
    for (int j = 0; j < 4; ++j) {
      gload16(pa + j * 8 * 512, &As[w * 2048 + j * 512]);
      gload16(pb + j * 8 * 512, &Bs[w * 2048 + j * 512]);
    }
    __syncthreads();
#pragma unroll
    for (int ks = 0; ks < 2; ++ks) {
      bf16x8 af[4], bfv[4];
#pragma unroll
      for (int mi = 0; mi < 4; ++mi)
        af[mi] = *(const bf16x8*)&As[(wr * 64 + mi * 16 + c16) * 64 + ks * 32 + g * 8];
#pragma unroll
      for (int ni = 0; ni < 4; ++ni)
        bfv[ni] = *(const bf16x8*)&Bs[(wc * 64 + ni * 16 + c16) * 64 + ks * 32 + g * 8];
#pragma unroll
      for (int mi = 0; mi < 4; ++mi)
#pragma unroll
        for (int ni = 0; ni < 4; ++ni)
          acc[mi][ni] = mfma16(af[mi], bfv[ni], acc[mi][ni]);
    }
    __syncthreads();
  }

  if (ct < 4) {
    // ---- q region: plain bf16 store, row-major [32768][512]
#pragma unroll
    for (int mi = 0; mi < 4; ++mi)
#pragma unroll
      for (int ni = 0; ni < 4; ++ni) {
        const int colg = col0 + wc * 64 + ni * 16 + c16;
#pragma unroll
        for (int r = 0; r < 4; ++r) {
          const int rowg = row0 + wr * 64 + mi * 16 + g * 4 + r;
          qb[rowg * 512 + colg] = f2bf(acc[mi][ni][r]);
        }
      }
  } else {
    // ---- k / v region: per-head LayerNorm then transposed store
    // wave quadrant (64 cols) == exactly one head's 64 dims
    const bool isK = ct < 8;
    const int h = (ct - (isK ? 4 : 8)) * 2 + wc;
    const float* gamma = isK ? gK : gV;
    const float* beta  = isK ? bK : bV;
    unsigned short* dst = isK ? knT : vnT;
    float gm[4], bt[4];
#pragma unroll
    for (int ni = 0; ni < 4; ++ni) {
      gm[ni] = gamma[h * 64 + ni * 16 + c16];
      bt[ni] = beta[h * 64 + ni * 16 + c16];
    }
    const int bidx = row0 >> 13;           // batch = row0/8192 (tiles never straddle)
    const int nbase = (row0 & 8191) + wr * 64;
    const int dbase = (bidx * 8 + h) * 64 * 8192;
#pragma unroll
    for (int mi = 0; mi < 4; ++mi) {
      float mean4[4], rs4[4];
#pragma unroll
      for (int r = 0; r < 4; ++r) {
        float a0 = acc[mi][0][r], a1 = acc[mi][1][r];
        float a2 = acc[mi][2][r], a3 = acc[mi][3][r];
        float s1 = a0 + a1 + a2 + a3;
        float s2 = a0 * a0 + a1 * a1 + a2 * a2 + a3 * a3;
#pragma unroll
        for (int m = 1; m <= 8; m <<= 1) {   // reduce over the 16-lane col group
          s1 += __shfl_xor(s1, m, 64);
          s2 += __shfl_xor(s2, m, 64);
        }
        const float mean = s1 * (1.0f / 64.0f);
        const float var = s2 * (1.0f / 64.0f) - mean * mean;
        mean4[r] = mean;
        rs4[r] = rsqrtf(var + 1e-5f);
      }
      const int n0 = nbase + mi * 16 + g * 4;
#pragma unroll
      for (int ni = 0; ni < 4; ++ni) {
        u16x4 o;
#pragma unroll
        for (int r = 0; r < 4; ++r)
          o[r] = f2bf((acc[mi][ni][r] - mean4[r]) * rs4[r] * gm[ni] + bt[ni]);
        // knT/vnT[bh][dim][n]: 4 consecutive n -> one 8B store
        *(u16x4*)&dst[dbase + (ni * 16 + c16) * 8192 + n0] = o;
      }
    }
  }
}

// --------------------------- K2: P = Kn^T Vn --------------------------------
// grid (32 bh, 32 n-chunks of 256), 256 threads; each wave does 64 n rows
__launch_bounds__(256)
__global__ void k2_kv_outer(const unsigned short* __restrict__ knT,
                            const unsigned short* __restrict__ vnT,
                            float* __restrict__ P) {
  const int bh = blockIdx.x;
  const int ch = blockIdx.y;
  const int tid = (int)threadIdx.x;
  const int l = tid & 63, w = tid >> 6;
  const int g = l >> 4, c16 = l & 15;
  const int nw = ch * 256 + w * 64;
  const int base = bh * 64 * 8192;

  f32x4 acc[4][4] = {};
#pragma unroll
  for (int ks = 0; ks < 2; ++ks) {
    const int n = nw + ks * 32 + g * 8;
    bf16x8 af[4], bfv[4];
#pragma unroll
    for (int mi = 0; mi < 4; ++mi)
      af[mi] = *(const bf16x8*)&knT[base + (mi * 16 + c16) * 8192 + n];
#pragma unroll
    for (int ni = 0; ni < 4; ++ni)
      bfv[ni] = *(const bf16x8*)&vnT[base + (ni * 16 + c16) * 8192 + n];
#pragma unroll
    for (int mi = 0; mi < 4; ++mi)
#pragma unroll
      for (int ni = 0; ni < 4; ++ni)
        acc[mi][ni] = mfma16(af[mi], bfv[ni], acc[mi][ni]);
  }
  float* Pp = P + bh * 4096;
#pragma unroll
  for (int mi = 0; mi < 4; ++mi)
#pragma unroll
    for (int ni = 0; ni < 4; ++ni)
#pragma unroll
      for (int r = 0; r < 4; ++r)
        atomicAdd(&Pp[(mi * 16 + g * 4 + r) * 64 + ni * 16 + c16], acc[mi][ni][r]);
}

// ----------------------- K2b: Pb = bf16(P / 8192) ---------------------------
__global__ void k2b_scale(const float* __restrict__ P,
                          unsigned short* __restrict__ Pbf) {
  int i = blockIdx.x * 256 + threadIdx.x;
  Pbf[i] = f2bf(P[i] * (1.0f / 8192.0f));
}

// --------------------------- K4a: out = q @ P -------------------------------
// grid (256 row-tiles, 8 heads), 256 threads; wave w handles 32 rows
__launch_bounds__(256)
__global__ void k4a_qp(const unsigned short* __restrict__ qb,
                       const unsigned short* __restrict__ Pbf,
                       unsigned short* __restrict__ outb) {
  __shared__ __align__(16) unsigned short Qs[128 * 64];
  __shared__ __align__(16) unsigned short Ps[64 * 64];
  const int rt = blockIdx.x;
  const int h = blockIdx.y;
  const int tid = (int)threadIdx.x;
  const int l = tid & 63, w = tid >> 6;
  const int g = l >> 4, c16 = l & 15;
  const int row0 = rt * 128;
  const int bh = (rt >> 6) * 8 + h;

  const unsigned short* gq = qb + (row0 + w * 32 + (l >> 3)) * 512 + h * 64 + (l & 7) * 8;
#pragma unroll
  for (int j = 0; j < 4; ++j)
    gload16(gq + j * 8 * 512, &Qs[w * 2048 + j * 512]);
  const unsigned short* gp = Pbf + bh * 4096 + (w * 16 + (l >> 3)) * 64 + (l & 7) * 8;
#pragma unroll
  for (int j = 0; j < 2; ++j)
    gload16(gp + j * 8 * 64, &Ps[w * 1024 + j * 512]);
  __syncthreads();

  f32x4 acc[2][4] = {};
#pragma unroll
  for (int ks = 0; ks < 2; ++ks) {
    bf16x8 af[2], bfv[4];
#pragma unroll
    for (int mi = 0; mi < 2; ++mi)
      af[mi] = *(const bf16x8*)&Qs[(w * 32 + mi * 16 + c16) * 64 + ks * 32 + g * 8];
#pragma unroll
    for (int ni = 0; ni < 4; ++ni) {
      bf16x8 t;
#pragma unroll
      for (int e = 0; e < 8; ++e)
        t[e] = (short)Ps[(ks * 32 + g * 8 + e) * 64 + ni * 16 + c16];
      bfv[ni] = t;
    }
#pragma unroll
    for (int mi = 0; mi < 2; ++mi)
#pragma unroll
      for (int ni = 0; ni < 4; ++ni)
        acc[mi][ni] = mfma16(af[mi], bfv[ni], acc[mi][ni]);
  }
#pragma unroll
  for (int mi = 0; mi < 2; ++mi)
#pragma unroll
    for (int ni = 0; ni < 4; ++ni)
#pragma unroll
      for (int r = 0; r < 4; ++r) {
        const int rowg = row0 + w * 32 + mi * 16 + g * 4 + r;
        outb[rowg * 512 + h * 64 + ni * 16 + c16] = f2bf(acc[mi][ni][r]);
      }
}

// ------------------- K4b: y = out @ W_out^T + b_out -------------------------
// grid (256, 4), 256 threads; same GEMM structure as K1
__launch_bounds__(256)
__global__ void k4b_proj(const unsigned short* __restrict__ outb,
                         const unsigned short* __restrict__ wob,
                         const float* __restrict__ bout,
                         float* __restrict__ y) {
  __shared__ __align__(16) unsigned short As[128 * 64];
  __shared__ __align__(16) unsigned short Bs[128 * 64];
  const int rt = blockIdx.x;
  const int ct = blockIdx.y;
  const int tid = (int)threadIdx.x;
  const int l = tid & 63, w = tid >> 6;
  const int wr = w >> 1, wc = w & 1;
  const int g = l >> 4, c16 = l & 15;
  const int row0 = rt * 128;
  const int col0 = ct * 128;

  const unsigned short* gsA = outb + (row0 + w * 32 + (l >> 3)) * 512 + (l & 7) * 8;
  const unsigned short* gsB = wob  + (col0 + w * 32 + (l >> 3)) * 512 + (l & 7) * 8;

  f32x4 acc[4][4] = {};
  for (int kt = 0; kt < 8; ++kt) {
    const unsigned short* pa = gsA + kt * 64;
    const unsigned short* pb = gsB + kt * 64;
#pragma unroll
    for (int j = 0; j < 4; ++j) {
      gload16(pa + j * 8 * 512, &As[w * 2048 + j * 512]);
      gload16(pb + j * 8 * 512, &Bs[w * 2048 + j * 512]);
    }
    __syncthreads();
#pragma unroll
    for (int ks = 0; ks < 2; ++ks) {
      bf16x8 af[4], bfv[4];
#pragma unroll
      for (int mi = 0; mi < 4; ++mi)
        af[mi] = *(const bf16x8*)&As[(wr * 64 + mi * 16 + c16) * 64 + ks * 32 + g * 8];
#pragma unroll
      for (int ni = 0; ni < 4; ++ni)
        bfv[ni] = *(const bf16x8*)&Bs[(wc * 64 + ni * 16 + c16) * 64 + ks * 32 + g * 8];
#pragma unroll
      for (int mi = 0; mi < 4; ++mi)
#pragma unroll
        for (int ni = 0; ni < 4; ++ni)
          acc[mi][ni] = mfma16(af[mi], bfv[ni], acc[mi][ni]);
    }
    __syncthreads();
  }

  float bo[4];
#pragma unroll
  for (int ni = 0; ni < 4; ++ni)
    bo[ni] = bout[col0 + wc * 64 + ni * 16 + c16];
#pragma unroll
  for (int mi = 0; mi < 4; ++mi)
#pragma unroll
    for (int ni = 0; ni < 4; ++ni) {
      const int colg = col0 + wc * 64 + ni * 16 + c16;
#pragma unroll
      for (int r = 0; r < 4; ++r) {
        const int rowg = row0 + wr * 64 + mi * 16 + g * 4 + r;
        y[rowg * 512 + colg] = acc[mi][ni][r] + bo[ni];
      }
    }
}

// ---------------------------------------------------------------------------
extern "C" void kernel_launch(void* const* d_in, const int* in_sizes, int n_in,
                              void* d_out, int out_size, void* d_ws, size_t ws_size,
                              hipStream_t stream) {
  (void)in_sizes; (void)n_in; (void)out_size; (void)ws_size;
  const float* x    = (const float*)d_in[0];
  const float* Wqkv = (const float*)d_in[1];
  const float* gK   = (const float*)d_in[2];
  const float* bK   = (const float*)d_in[3];
  const float* gV   = (const float*)d_in[4];
  const float* bV   = (const float*)d_in[5];
  const float* Wout = (const float*)d_in[6];
  const float* bout = (const float*)d_in[7];
  float* y = (float*)d_out;

  // workspace carve (137 MB total); xb region is reused as outb after K1
  char* w = (char*)d_ws;
  unsigned short* xb   = (unsigned short*)(w);              // 33,554,432 B
  unsigned short* qb   = (unsigned short*)(w + 33554432);   // 33,554,432 B
  unsigned short* knT  = (unsigned short*)(w + 67108864);   // 33,554,432 B
  unsigned short* vnT  = (unsigned short*)(w + 100663296);  // 33,554,432 B
  unsigned short* Wb   = (unsigned short*)(w + 134217728);  //  1,572,864 B
  unsigned short* Wob  = (unsigned short*)(w + 135790592);  //    524,288 B
  float*          P    = (float*)         (w + 136314880);  //    524,288 B
  unsigned short* Pbf  = (unsigned short*)(w + 136839168);  //    262,144 B
  unsigned short* outb = xb;  // alias: xb dead after k1

  k_cvt_bf16<<<16384, 256, 0, stream>>>(x, xb, 16777216 / 4);
  k_cvt_bf16<<<768, 256, 0, stream>>>(Wqkv, Wb, 786432 / 4);
  k_cvt_bf16<<<256, 256, 0, stream>>>(Wout, Wob, 262144 / 4);
  hipMemsetAsync(P, 0, 524288, stream);

  k1_qkv_ln<<<dim3(256, 12), 256, 0, stream>>>(xb, Wb, gK, bK, gV, bV, qb, knT, vnT);
  k2_kv_outer<<<dim3(32, 32), 256, 0, stream>>>(knT, vnT, P);
  k2b_scale<<<512, 256, 0, stream>>>(P, Pbf);
  k4a_qp<<<dim3(256, 8), 256, 0, stream>>>(qb, Pbf, outb);
  k4b_proj<<<dim3(256, 4), 256, 0, stream>>>(outb, Wob, bout, y);
}

// Round 2
// 161.746 us; speedup vs baseline: 1.5399x; 1.5399x over previous
//
#include <hip/hip_runtime.h>

// ---------------------------------------------------------------------------
// GalerkinAttention on MI355X (gfx950), bf16 MFMA pipeline, round 2.
//
// Shapes: B=4, N=8192, D=512, H=8, Dh=64, BN=32768 rows.
//
// Algebraic refactor: y = x @ M_b^T + b_out, where per batch b
//   M_b[d',d] = sum_h W_out[d', h*64+dv] * P_bh[dh,dv] * W_q[h*64+dh, d] / n
// so q and out are never materialized.
//
// Pipeline:
//   K0 : convert x, W_qkv, W_out to bf16
//   K1 : kv = x @ W_kv^T (128x128 tiles, 2-phase dbuf, swizzled LDS)
//        epilogue: per-head LayerNorm, store transposed knT/vnT [bh][64][8192]
//   K2 : P[bh] += Kn^T Vn  (MFMA from global, fp32 atomicAdd, 4 slabs/wave)
//   K3a: Gt[b][d][h*64+dv] = sum_dh P[bh][dh][dv] * Wqkv[h*64+dh][d] / 8192
//   K3b: M_b = Wout_bf @ Gt_b^T-contraction (bf16 GEMM, K=512)
//   K4 : y = xb @ M_b^T + b_out (bf16 GEMM, fp32 store)
//
// MFMA 16x16x32 bf16 conventions (verified round 1):
//   A frag: lane l holds A[row=l&15][k = ks*32 + (l>>4)*8 + e]
//   B frag: lane l holds B[col=l&15][same k]  (B staged row-major [col][K])
//   C/D   : lane l reg r -> C[row=(l>>4)*4+r][col=l&15]
//
// LDS swizzle (tile [128 rows][64 shorts], 128-B rows):
//   physical_byte = row*128 + (col_byte ^ ((row&7)<<4))
//   global_load_lds writes linearly -> pre-swizzle the GLOBAL source column
//   (lane l stages logical cols ((l&7)^(l>>3))*8), swizzle the ds_read addr.
// ---------------------------------------------------------------------------

typedef __attribute__((ext_vector_type(8))) short bf16x8;
typedef __attribute__((ext_vector_type(4))) float f32x4;
typedef __attribute__((ext_vector_type(4))) unsigned short u16x4;

__device__ __forceinline__ unsigned short f2bf(float f) {
  unsigned int u = __builtin_bit_cast(unsigned int, f);
  u += 0x7FFFu + ((u >> 16) & 1u);   // RNE
  return (unsigned short)(u >> 16);
}

__device__ __forceinline__ f32x4 mfma16(bf16x8 a, bf16x8 b, f32x4 c) {
  return __builtin_amdgcn_mfma_f32_16x16x32_bf16(a, b, c, 0, 0, 0);
}

__device__ __forceinline__ void gload16(const void* g, void* l) {
  __builtin_amdgcn_global_load_lds(
      (const __attribute__((address_space(1))) void*)g,
      (__attribute__((address_space(3))) void*)l, 16, 0, 0);
}

// ------------------------------- K0: convert -------------------------------
__global__ void k_cvt_bf16(const float* __restrict__ src,
                           unsigned short* __restrict__ dst, int n4) {
  int i = blockIdx.x * blockDim.x + threadIdx.x;
  if (i < n4) {
    float4 v = ((const float4*)src)[i];
    u16x4 o;
    o[0] = f2bf(v.x); o[1] = f2bf(v.y); o[2] = f2bf(v.z); o[3] = f2bf(v.w);
    ((u16x4*)dst)[i] = o;
  }
}

// ----------------------- shared 128x128 GEMM pieces -------------------------
// stage one [128][64] bf16 tile pair into LDS (linear dest, pre-swizzled src)
__device__ __forceinline__ void stage_tile(const unsigned short* pa,
                                           const unsigned short* pb,
                                           unsigned short* As, unsigned short* Bs,
                                           int w) {
#pragma unroll
  for (int j = 0; j < 4; ++j) {
    gload16(pa + j * 8 * 512, As + w * 2048 + j * 512);
    gload16(pb + j * 8 * 512, Bs + w * 2048 + j * 512);
  }
}

// 32 MFMAs on one staged tile pair (swizzled ds_read)
__device__ __forceinline__ void compute_tile(const unsigned short* As,
                                             const unsigned short* Bs,
                                             int wr, int wc, int g, int c16,
                                             f32x4 acc[4][4]) {
#pragma unroll
  for (int ks = 0; ks < 2; ++ks) {
    const int kcol = (ks * 32 + g * 8) ^ ((c16 & 7) << 3);
    bf16x8 af[4], bfv[4];
#pragma unroll
    for (int mi = 0; mi < 4; ++mi)
      af[mi] = *(const bf16x8*)&As[(wr * 64 + mi * 16 + c16) * 64 + kcol];
#pragma unroll
    for (int ni = 0; ni < 4; ++ni)
      bfv[ni] = *(const bf16x8*)&Bs[(wc * 64 + ni * 16 + c16) * 64 + kcol];
#pragma unroll
    for (int mi = 0; mi < 4; ++mi)
#pragma unroll
      for (int ni = 0; ni < 4; ++ni)
        acc[mi][ni] = mfma16(af[mi], bfv[ni], acc[mi][ni]);
  }
}

// ------------------------- K1: kv GEMM + fused LN ---------------------------
// grid (256 row-tiles, 8 col-tiles over k|v), 256 threads (4 waves, 2x2)
__launch_bounds__(256)
__global__ void k1_kv_ln(const unsigned short* __restrict__ xb,
                         const unsigned short* __restrict__ wqkvb,
                         const float* __restrict__ gK, const float* __restrict__ bK,
                         const float* __restrict__ gV, const float* __restrict__ bV,
                         unsigned short* __restrict__ knT,
                         unsigned short* __restrict__ vnT) {
  __shared__ __align__(16) unsigned short As[2][8192];
  __shared__ __align__(16) unsigned short Bs[2][8192];
  const int rt = blockIdx.x, ct = blockIdx.y;
  const int tid = (int)threadIdx.x;
  const int l = tid & 63, w = tid >> 6;
  const int wr = w >> 1, wc = w & 1;
  const int g = l >> 4, c16 = l & 15;
  const int row0 = rt * 128;
  const int colq = 512 + ct * 128;     // k: cols 512..1023, v: 1024..1535
  const int swz = ((l & 7) ^ (l >> 3)) * 8;

  const unsigned short* gsA = xb    + (row0 + w * 32 + (l >> 3)) * 512 + swz;
  const unsigned short* gsB = wqkvb + (colq + w * 32 + (l >> 3)) * 512 + swz;

  f32x4 acc[4][4] = {};
  stage_tile(gsA, gsB, As[0], Bs[0], w);
  __syncthreads();
  for (int kt = 0; kt < 7; ++kt) {
    stage_tile(gsA + (kt + 1) * 64, gsB + (kt + 1) * 64,
               As[(kt + 1) & 1], Bs[(kt + 1) & 1], w);
    compute_tile(As[kt & 1], Bs[kt & 1], wr, wc, g, c16, acc);
    __syncthreads();
  }
  compute_tile(As[1], Bs[1], wr, wc, g, c16, acc);

  // ---- per-head LayerNorm epilogue; transposed store [bh][64][8192]
  const bool isK = ct < 4;
  const int h = (ct & 3) * 2 + wc;     // wave col-half == one head's 64 dims
  const float* gamma = isK ? gK : gV;
  const float* beta  = isK ? bK : bV;
  unsigned short* dst = isK ? knT : vnT;
  float gm[4], bt[4];
#pragma unroll
  for (int ni = 0; ni < 4; ++ni) {
    gm[ni] = gamma[h * 64 + ni * 16 + c16];
    bt[ni] = beta[h * 64 + ni * 16 + c16];
  }
  const int bidx = row0 >> 13;
  const int nbase = (row0 & 8191) + wr * 64;
  const int dbase = (bidx * 8 + h) * 64 * 8192;
#pragma unroll
  for (int mi = 0; mi < 4; ++mi) {
    float mean4[4], rs4[4];
#pragma unroll
    for (int r = 0; r < 4; ++r) {
      float a0 = acc[mi][0][r], a1 = acc[mi][1][r];
      float a2 = acc[mi][2][r], a3 = acc[mi][3][r];
      float s1 = a0 + a1 + a2 + a3;
      float s2 = a0 * a0 + a1 * a1 + a2 * a2 + a3 * a3;
#pragma unroll
      for (int m = 1; m <= 8; m <<= 1) {
        s1 += __shfl_xor(s1, m, 64);
        s2 += __shfl_xor(s2, m, 64);
      }
      const float mean = s1 * (1.0f / 64.0f);
      const float var = s2 * (1.0f / 64.0f) - mean * mean;
      mean4[r] = mean;
      rs4[r] = rsqrtf(var + 1e-5f);
    }
    const int n0 = nbase + mi * 16 + g * 4;
#pragma unroll
    for (int ni = 0; ni < 4; ++ni) {
      u16x4 o;
#pragma unroll
      for (int r = 0; r < 4; ++r)
        o[r] = f2bf((acc[mi][ni][r] - mean4[r]) * rs4[r] * gm[ni] + bt[ni]);
      *(u16x4*)&dst[dbase + (ni * 16 + c16) * 8192 + n0] = o;
    }
  }
}

// --------------------------- K2: P = Kn^T Vn --------------------------------
// grid (32 bh, 8 chunks of 1024 n), 256 threads; 4 n-slabs accumulated per
// wave before the atomic (4x fewer atomics than round 1)
__launch_bounds__(256)
__global__ void k2_kv_outer(const unsigned short* __restrict__ knT,
                            const unsigned short* __restrict__ vnT,
                            float* __restrict__ P) {
  const int bh = blockIdx.x, ch = blockIdx.y;
  const int tid = (int)threadIdx.x;
  const int l = tid & 63, w = tid >> 6;
  const int g = l >> 4, c16 = l & 15;
  const int base = bh * 64 * 8192;

  f32x4 acc[4][4] = {};
  for (int it = 0; it < 4; ++it) {
    const int nw = ch * 1024 + it * 256 + w * 64;
#pragma unroll
    for (int ks = 0; ks < 2; ++ks) {
      const int n = nw + ks * 32 + g * 8;
      bf16x8 af[4], bfv[4];
#pragma unroll
      for (int mi = 0; mi < 4; ++mi)
        af[mi] = *(const bf16x8*)&knT[base + (mi * 16 + c16) * 8192 + n];
#pragma unroll
      for (int ni = 0; ni < 4; ++ni)
        bfv[ni] = *(const bf16x8*)&vnT[base + (ni * 16 + c16) * 8192 + n];
#pragma unroll
      for (int mi = 0; mi < 4; ++mi)
#pragma unroll
        for (int ni = 0; ni < 4; ++ni)
          acc[mi][ni] = mfma16(af[mi], bfv[ni], acc[mi][ni]);
    }
  }
  float* Pp = P + bh * 4096;
#pragma unroll
  for (int mi = 0; mi < 4; ++mi)
#pragma unroll
    for (int ni = 0; ni < 4; ++ni)
#pragma unroll
      for (int r = 0; r < 4; ++r)
        atomicAdd(&Pp[(mi * 16 + g * 4 + r) * 64 + ni * 16 + c16], acc[mi][ni][r]);
}

// ------------- K3a: Gt[b][d][h*64+dv] = sum_dh P[bh][dh][dv]*Wq[h*64+dh][d]/n
// grid (32 bh, 8 d-blocks of 64), 256 threads
__launch_bounds__(256)
__global__ void k3a_g(const float* __restrict__ Wqkv,
                      const float* __restrict__ P,
                      unsigned short* __restrict__ Gt) {
  __shared__ float Pl[64 * 64];
  const int bh = blockIdx.x, dd = blockIdx.y;
  const int b = bh >> 3, h = bh & 7;
  const int t = (int)threadIdx.x;
  for (int i = t; i < 1024; i += 256)
    ((float4*)Pl)[i] = ((const float4*)(P + bh * 4096))[i];
  __syncthreads();

  const int qg = t >> 6, dl = t & 63;
  const int d = dd * 64 + dl;
  float acc[16] = {};
  for (int dh = 0; dh < 64; ++dh) {
    const float wq = Wqkv[(h * 64 + dh) * 512 + d];
    const float* pr = &Pl[dh * 64 + qg * 16];
#pragma unroll
    for (int i = 0; i < 16; ++i) acc[i] += pr[i] * wq;
  }
  unsigned short* go = &Gt[(b * 512 + d) * 512 + h * 64 + qg * 16];
#pragma unroll
  for (int i = 0; i < 16; ++i) go[i] = f2bf(acc[i] * (1.0f / 8192.0f));
}

// ----------- K3b: M_b[d'][d] = sum_e Wout[d'][e] * Gt_b[d][e]  (bf16 out) ---
// grid (4 rt, 4 ct, 4 b), 256 threads
__launch_bounds__(256)
__global__ void k3b_m(const unsigned short* __restrict__ wob,
                      const unsigned short* __restrict__ Gt,
                      unsigned short* __restrict__ Mb) {
  __shared__ __align__(16) unsigned short As[2][8192];
  __shared__ __align__(16) unsigned short Bs[2][8192];
  const int rt = blockIdx.x, ct = blockIdx.y, b = blockIdx.z;
  const int tid = (int)threadIdx.x;
  const int l = tid & 63, w = tid >> 6;
  const int wr = w >> 1, wc = w & 1;
  const int g = l >> 4, c16 = l & 15;
  const int row0 = rt * 128, col0 = ct * 128;
  const int swz = ((l & 7) ^ (l >> 3)) * 8;

  const unsigned short* gsA = wob + (row0 + w * 32 + (l >> 3)) * 512 + swz;
  const unsigned short* gsB = Gt + b * 262144 + (col0 + w * 32 + (l >> 3)) * 512 + swz;

  f32x4 acc[4][4] = {};
  stage_tile(gsA, gsB, As[0], Bs[0], w);
  __syncthreads();
  for (int kt = 0; kt < 7; ++kt) {
    stage_tile(gsA + (kt + 1) * 64, gsB + (kt + 1) * 64,
               As[(kt + 1) & 1], Bs[(kt + 1) & 1], w);
    compute_tile(As[kt & 1], Bs[kt & 1], wr, wc, g, c16, acc);
    __syncthreads();
  }
  compute_tile(As[1], Bs[1], wr, wc, g, c16, acc);

#pragma unroll
  for (int mi = 0; mi < 4; ++mi)
#pragma unroll
    for (int ni = 0; ni < 4; ++ni) {
      const int colg = col0 + wc * 64 + ni * 16 + c16;
#pragma unroll
      for (int r = 0; r < 4; ++r) {
        const int rowg = row0 + wr * 64 + mi * 16 + g * 4 + r;
        Mb[(b * 512 + rowg) * 512 + colg] = f2bf(acc[mi][ni][r]);
      }
    }
}

// ---------------- K4: y = xb @ M_b^T + b_out (fp32 store) -------------------
// grid (256 rt, 4 ct), 256 threads
__launch_bounds__(256)
__global__ void k4_final(const unsigned short* __restrict__ xb,
                         const unsigned short* __restrict__ Mb,
                         const float* __restrict__ bout,
                         float* __restrict__ y) {
  __shared__ __align__(16) unsigned short As[2][8192];
  __shared__ __align__(16) unsigned short Bs[2][8192];
  const int rt = blockIdx.x, ct = blockIdx.y;
  const int tid = (int)threadIdx.x;
  const int l = tid & 63, w = tid >> 6;
  const int wr = w >> 1, wc = w & 1;
  const int g = l >> 4, c16 = l & 15;
  const int row0 = rt * 128, col0 = ct * 128;
  const int bb = row0 >> 13;
  const int swz = ((l & 7) ^ (l >> 3)) * 8;

  const unsigned short* gsA = xb + (row0 + w * 32 + (l >> 3)) * 512 + swz;
  const unsigned short* gsB = Mb + bb * 262144 + (col0 + w * 32 + (l >> 3)) * 512 + swz;

  f32x4 acc[4][4] = {};
  stage_tile(gsA, gsB, As[0], Bs[0], w);
  __syncthreads();
  for (int kt = 0; kt < 7; ++kt) {
    stage_tile(gsA + (kt + 1) * 64, gsB + (kt + 1) * 64,
               As[(kt + 1) & 1], Bs[(kt + 1) & 1], w);
    compute_tile(As[kt & 1], Bs[kt & 1], wr, wc, g, c16, acc);
    __syncthreads();
  }
  compute_tile(As[1], Bs[1], wr, wc, g, c16, acc);

  float bo[4];
#pragma unroll
  for (int ni = 0; ni < 4; ++ni)
    bo[ni] = bout[col0 + wc * 64 + ni * 16 + c16];
#pragma unroll
  for (int mi = 0; mi < 4; ++mi)
#pragma unroll
    for (int ni = 0; ni < 4; ++ni) {
      const int colg = col0 + wc * 64 + ni * 16 + c16;
#pragma unroll
      for (int r = 0; r < 4; ++r) {
        const int rowg = row0 + wr * 64 + mi * 16 + g * 4 + r;
        y[rowg * 512 + colg] = acc[mi][ni][r] + bo[ni];
      }
    }
}

// ---------------------------------------------------------------------------
extern "C" void kernel_launch(void* const* d_in, const int* in_sizes, int n_in,
                              void* d_out, int out_size, void* d_ws, size_t ws_size,
                              hipStream_t stream) {
  (void)in_sizes; (void)n_in; (void)out_size; (void)ws_size;
  const float* x    = (const float*)d_in[0];
  const float* Wqkv = (const float*)d_in[1];
  const float* gK   = (const float*)d_in[2];
  const float* bK   = (const float*)d_in[3];
  const float* gV   = (const float*)d_in[4];
  const float* bV   = (const float*)d_in[5];
  const float* Wout = (const float*)d_in[6];
  const float* bout = (const float*)d_in[7];
  float* y = (float*)d_out;

  // workspace carve (~107.5 MB)
  char* w = (char*)d_ws;
  unsigned short* xb  = (unsigned short*)(w);              // 33,554,432
  unsigned short* knT = (unsigned short*)(w + 33554432);   // 33,554,432
  unsigned short* vnT = (unsigned short*)(w + 67108864);   // 33,554,432
  unsigned short* Wb  = (unsigned short*)(w + 100663296);  //  1,572,864
  unsigned short* Wob = (unsigned short*)(w + 102236160);  //    524,288
  float*          P   = (float*)         (w + 102760448);  //    524,288
  unsigned short* Gt  = (unsigned short*)(w + 103284736);  //  2,097,152
  unsigned short* Mb  = (unsigned short*)(w + 105381888);  //  2,097,152

  k_cvt_bf16<<<16384, 256, 0, stream>>>(x, xb, 4194304);
  k_cvt_bf16<<<768, 256, 0, stream>>>(Wqkv, Wb, 196608);
  k_cvt_bf16<<<256, 256, 0, stream>>>(Wout, Wob, 65536);
  hipMemsetAsync(P, 0, 524288, stream);

  k1_kv_ln<<<dim3(256, 8), 256, 0, stream>>>(xb, Wb, gK, bK, gV, bV, knT, vnT);
  k2_kv_outer<<<dim3(32, 8), 256, 0, stream>>>(knT, vnT, P);
  k3a_g<<<dim3(32, 8), 256, 0, stream>>>(Wqkv, P, Gt);
  k3b_m<<<dim3(4, 4, 4), 256, 0, stream>>>(Wob, Gt, Mb);
  k4_final<<<dim3(256, 4), 256, 0, stream>>>(xb, Mb, bout, y);
}

// Round 3
// 145.938 us; speedup vs baseline: 1.7067x; 1.1083x over previous
//
#include <hip/hip_runtime.h>

// ---------------------------------------------------------------------------
// GalerkinAttention on MI355X (gfx950), bf16 MFMA pipeline, round 3.
//
// Shapes: B=4, N=8192, D=512, H=8, Dh=64, BN=32768 rows.
//
// Algebra: y = x @ M_b^T + b_out,
//   M_b[d'][d] = sum_h W_out[d', h-blk] . P_bh . W_q[h-blk, d] / n
//
// Pipeline:
//   K0 : convert x, W_qkv, W_out to bf16
//   K1 : per (row-tile, head): kv = x @ W_{k|v,h}^T (128x128, 2-phase dbuf,
//        swizzled LDS); epilogue: in-register per-head LayerNorm ->
//        kn/vn to LDS (16B-XOR transposed layout) -> P-partial MFMA ->
//        atomicAdd into P[bh] (fp32). kn/vn NEVER hit global memory.
//   K3a: Gt[b][d][h*64+dv] = sum_dh P[bh][dh][dv] * Wqkv[h*64+dh][d] / 8192
//   K3b: M_b = Wout_bf16 @ Gt_b (bf16 GEMM, K=512)
//   K4 : y = xb @ M_b^T + b_out (bf16 GEMM, fp32 store)
//
// MFMA 16x16x32 bf16 (verified rounds 1-2):
//   A frag: lane l holds A[row=l&15][k = ks*32 + (l>>4)*8 + e]
//   B frag: lane l holds B[col=l&15][same k]
//   C/D   : lane l reg r -> C[row=(l>>4)*4+r][col=l&15]
//
// Main-loop LDS swizzle (8-short granular XOR, verified round 2):
//   stage source pre-swizzled with ((l&7)^(l>>3))*8; ds_read col ^ ((c16&7)<<3)
// Epilogue kn/vn LDS layout ([64 d][128 n] bf16, 16B-granular XOR):
//   phys_short(d, n) = d*128 + ((n>>3) ^ (d&15))*8 + (n&7)
//   -> read of 8 consecutive n at 8-aligned n0: identity k-mapping per lane,
//      2-way bank aliasing only (free per m136).
// ---------------------------------------------------------------------------

typedef __attribute__((ext_vector_type(8))) short bf16x8;
typedef __attribute__((ext_vector_type(4))) float f32x4;
typedef __attribute__((ext_vector_type(4))) unsigned short u16x4;

__device__ __forceinline__ unsigned short f2bf(float f) {
  unsigned int u = __builtin_bit_cast(unsigned int, f);
  u += 0x7FFFu + ((u >> 16) & 1u);   // RNE
  return (unsigned short)(u >> 16);
}

__device__ __forceinline__ f32x4 mfma16(bf16x8 a, bf16x8 b, f32x4 c) {
  return __builtin_amdgcn_mfma_f32_16x16x32_bf16(a, b, c, 0, 0, 0);
}

__device__ __forceinline__ void gload16(const void* g, void* l) {
  __builtin_amdgcn_global_load_lds(
      (const __attribute__((address_space(1))) void*)g,
      (__attribute__((address_space(3))) void*)l, 16, 0, 0);
}

// ------------------------------- K0: convert -------------------------------
__global__ void k_cvt_bf16(const float* __restrict__ src,
                           unsigned short* __restrict__ dst, int n4) {
  int i = blockIdx.x * blockDim.x + threadIdx.x;
  if (i < n4) {
    float4 v = ((const float4*)src)[i];
    u16x4 o;
    o[0] = f2bf(v.x); o[1] = f2bf(v.y); o[2] = f2bf(v.z); o[3] = f2bf(v.w);
    ((u16x4*)dst)[i] = o;
  }
}

// ----------------------- shared 128x128 GEMM pieces -------------------------
__device__ __forceinline__ void stage_tile(const unsigned short* pa,
                                           const unsigned short* pb,
                                           unsigned short* As, unsigned short* Bs,
                                           int w) {
#pragma unroll
  for (int j = 0; j < 4; ++j) {
    gload16(pa + j * 8 * 512, As + w * 2048 + j * 512);
    gload16(pb + j * 8 * 512, Bs + w * 2048 + j * 512);
  }
}

__device__ __forceinline__ void compute_tile(const unsigned short* As,
                                             const unsigned short* Bs,
                                             int wr, int wc, int g, int c16,
                                             f32x4 acc[4][4]) {
#pragma unroll
  for (int ks = 0; ks < 2; ++ks) {
    const int kcol = (ks * 32 + g * 8) ^ ((c16 & 7) << 3);
    bf16x8 af[4], bfv[4];
#pragma unroll
    for (int mi = 0; mi < 4; ++mi)
      af[mi] = *(const bf16x8*)&As[(wr * 64 + mi * 16 + c16) * 64 + kcol];
#pragma unroll
    for (int ni = 0; ni < 4; ++ni)
      bfv[ni] = *(const bf16x8*)&Bs[(wc * 64 + ni * 16 + c16) * 64 + kcol];
#pragma unroll
    for (int mi = 0; mi < 4; ++mi)
#pragma unroll
      for (int ni = 0; ni < 4; ++ni)
        acc[mi][ni] = mfma16(af[mi], bfv[ni], acc[mi][ni]);
  }
}

// ---------------- K1: kv GEMM + LN + fused P-accumulation -------------------
// grid (256 row-tiles, 8 heads), 256 threads (4 waves: wc=0 -> k, wc=1 -> v)
__launch_bounds__(256)
__global__ void k1_kvp(const unsigned short* __restrict__ xb,
                       const unsigned short* __restrict__ wqkvb,
                       const float* __restrict__ gK, const float* __restrict__ bK,
                       const float* __restrict__ gV, const float* __restrict__ bV,
                       float* __restrict__ P) {
  __shared__ __align__(16) unsigned short As[2][8192];
  __shared__ __align__(16) unsigned short Bs[2][8192];
  const int rt = blockIdx.x, h = blockIdx.y;
  const int tid = (int)threadIdx.x;
  const int l = tid & 63, w = tid >> 6;
  const int wr = w >> 1, wc = w & 1;
  const int g = l >> 4, c16 = l & 15;
  const int row0 = rt * 128;
  const int swz = ((l & 7) ^ (l >> 3)) * 8;

  const unsigned short* gsA = xb + (row0 + w * 32 + (l >> 3)) * 512 + swz;
  // B tile cols: 0..63 = k-head h (wqkv rows 512+h*64..), 64..127 = v-head h
  const int bcol = (w < 2) ? (512 + h * 64 + w * 32) : (1024 + h * 64 + (w - 2) * 32);
  const unsigned short* gsB = wqkvb + (bcol + (l >> 3)) * 512 + swz;

  f32x4 acc[4][4] = {};
  stage_tile(gsA, gsB, As[0], Bs[0], w);
  __syncthreads();
  for (int kt = 0; kt < 7; ++kt) {
    stage_tile(gsA + (kt + 1) * 64, gsB + (kt + 1) * 64,
               As[(kt + 1) & 1], Bs[(kt + 1) & 1], w);
    compute_tile(As[kt & 1], Bs[kt & 1], wr, wc, g, c16, acc);
    __syncthreads();
  }
  compute_tile(As[1], Bs[1], wr, wc, g, c16, acc);
  // after this point all waves only read As[1]/Bs[1]; As[0]/Bs[0] are free

  // ---- per-head LayerNorm (wave col-half == head h's 64 dims; wc: k or v)
  const float* gamma = (wc == 0) ? gK : gV;
  const float* beta  = (wc == 0) ? bK : bV;
  float gm[4], bt[4];
#pragma unroll
  for (int ni = 0; ni < 4; ++ni) {
    gm[ni] = gamma[h * 64 + ni * 16 + c16];
    bt[ni] = beta[h * 64 + ni * 16 + c16];
  }

  // kn -> Kl (=As[0] region, 64x128 bf16), vn -> Vl (=Bs[0] region)
  unsigned short* Kl = &As[0][0];
  unsigned short* Vl = &Bs[0][0];
  unsigned short* dst = (wc == 0) ? Kl : Vl;

#pragma unroll
  for (int mi = 0; mi < 4; ++mi) {
    float mean4[4], rs4[4];
#pragma unroll
    for (int r = 0; r < 4; ++r) {
      float a0 = acc[mi][0][r], a1 = acc[mi][1][r];
      float a2 = acc[mi][2][r], a3 = acc[mi][3][r];
      float s1 = a0 + a1 + a2 + a3;
      float s2 = a0 * a0 + a1 * a1 + a2 * a2 + a3 * a3;
#pragma unroll
      for (int m = 1; m <= 8; m <<= 1) {   // reduce over 16-lane col group
        s1 += __shfl_xor(s1, m, 64);
        s2 += __shfl_xor(s2, m, 64);
      }
      const float mean = s1 * (1.0f / 64.0f);
      const float var = s2 * (1.0f / 64.0f) - mean * mean;
      mean4[r] = mean;
      rs4[r] = rsqrtf(var + 1e-5f);
    }
    const int n0 = wr * 64 + mi * 16 + g * 4;   // block-local n of r=0
#pragma unroll
    for (int ni = 0; ni < 4; ++ni) {
      const int d = ni * 16 + c16;
      u16x4 o;
#pragma unroll
      for (int r = 0; r < 4; ++r)
        o[r] = f2bf((acc[mi][ni][r] - mean4[r]) * rs4[r] * gm[ni] + bt[ni]);
      // transposed, 16B-granular XOR swizzle: phys8 = (n>>3) ^ (d&15)
      *(u16x4*)&dst[d * 128 + (((n0 >> 3) ^ c16) << 3) + (n0 & 7)] = o;
    }
  }
  __syncthreads();

  // ---- P-partial: wave w computes dh rows w*16..w*16+15, all 64 dv
  f32x4 pacc[4] = {};
#pragma unroll
  for (int ks = 0; ks < 4; ++ks) {
    const int p8 = (ks * 4 + g);                 // logical n/8 block
    bf16x8 af = *(const bf16x8*)&Kl[(w * 16 + c16) * 128 + ((p8 ^ c16) << 3)];
#pragma unroll
    for (int ni = 0; ni < 4; ++ni) {
      bf16x8 bfv = *(const bf16x8*)&Vl[(ni * 16 + c16) * 128 + ((p8 ^ c16) << 3)];
      pacc[ni] = mfma16(af, bfv, pacc[ni]);
    }
  }
  const int bh = (row0 >> 13) * 8 + h;
  float* Pp = P + bh * 4096;
#pragma unroll
  for (int ni = 0; ni < 4; ++ni)
#pragma unroll
    for (int r = 0; r < 4; ++r)
      atomicAdd(&Pp[(w * 16 + g * 4 + r) * 64 + ni * 16 + c16], pacc[ni][r]);
}

// ------------- K3a: Gt[b][d][h*64+dv] = sum_dh P[bh][dh][dv]*Wq[h*64+dh][d]/n
__launch_bounds__(256)
__global__ void k3a_g(const float* __restrict__ Wqkv,
                      const float* __restrict__ P,
                      unsigned short* __restrict__ Gt) {
  __shared__ float Pl[64 * 64];
  const int bh = blockIdx.x, dd = blockIdx.y;
  const int b = bh >> 3, h = bh & 7;
  const int t = (int)threadIdx.x;
  for (int i = t; i < 1024; i += 256)
    ((float4*)Pl)[i] = ((const float4*)(P + bh * 4096))[i];
  __syncthreads();

  const int qg = t >> 6, dl = t & 63;
  const int d = dd * 64 + dl;
  float acc[16] = {};
  for (int dh = 0; dh < 64; ++dh) {
    const float wq = Wqkv[(h * 64 + dh) * 512 + d];
    const float* pr = &Pl[dh * 64 + qg * 16];
#pragma unroll
    for (int i = 0; i < 16; ++i) acc[i] += pr[i] * wq;
  }
  unsigned short* go = &Gt[(b * 512 + d) * 512 + h * 64 + qg * 16];
#pragma unroll
  for (int i = 0; i < 16; ++i) go[i] = f2bf(acc[i] * (1.0f / 8192.0f));
}

// ----------- K3b: M_b[d'][d] = sum_e Wout[d'][e] * Gt_b[d][e] ---------------
__launch_bounds__(256)
__global__ void k3b_m(const unsigned short* __restrict__ wob,
                      const unsigned short* __restrict__ Gt,
                      unsigned short* __restrict__ Mb) {
  __shared__ __align__(16) unsigned short As[2][8192];
  __shared__ __align__(16) unsigned short Bs[2][8192];
  const int rt = blockIdx.x, ct = blockIdx.y, b = blockIdx.z;
  const int tid = (int)threadIdx.x;
  const int l = tid & 63, w = tid >> 6;
  const int wr = w >> 1, wc = w & 1;
  const int g = l >> 4, c16 = l & 15;
  const int row0 = rt * 128, col0 = ct * 128;
  const int swz = ((l & 7) ^ (l >> 3)) * 8;

  const unsigned short* gsA = wob + (row0 + w * 32 + (l >> 3)) * 512 + swz;
  const unsigned short* gsB = Gt + b * 262144 + (col0 + w * 32 + (l >> 3)) * 512 + swz;

  f32x4 acc[4][4] = {};
  stage_tile(gsA, gsB, As[0], Bs[0], w);
  __syncthreads();
  for (int kt = 0; kt < 7; ++kt) {
    stage_tile(gsA + (kt + 1) * 64, gsB + (kt + 1) * 64,
               As[(kt + 1) & 1], Bs[(kt + 1) & 1], w);
    compute_tile(As[kt & 1], Bs[kt & 1], wr, wc, g, c16, acc);
    __syncthreads();
  }
  compute_tile(As[1], Bs[1], wr, wc, g, c16, acc);

#pragma unroll
  for (int mi = 0; mi < 4; ++mi)
#pragma unroll
    for (int ni = 0; ni < 4; ++ni) {
      const int colg = col0 + wc * 64 + ni * 16 + c16;
#pragma unroll
      for (int r = 0; r < 4; ++r) {
        const int rowg = row0 + wr * 64 + mi * 16 + g * 4 + r;
        Mb[(b * 512 + rowg) * 512 + colg] = f2bf(acc[mi][ni][r]);
      }
    }
}

// ---------------- K4: y = xb @ M_b^T + b_out (fp32 store) -------------------
__launch_bounds__(256)
__global__ void k4_final(const unsigned short* __restrict__ xb,
                         const unsigned short* __restrict__ Mb,
                         const float* __restrict__ bout,
                         float* __restrict__ y) {
  __shared__ __align__(16) unsigned short As[2][8192];
  __shared__ __align__(16) unsigned short Bs[2][8192];
  const int rt = blockIdx.x, ct = blockIdx.y;
  const int tid = (int)threadIdx.x;
  const int l = tid & 63, w = tid >> 6;
  const int wr = w >> 1, wc = w & 1;
  const int g = l >> 4, c16 = l & 15;
  const int row0 = rt * 128, col0 = ct * 128;
  const int bb = row0 >> 13;
  const int swz = ((l & 7) ^ (l >> 3)) * 8;

  const unsigned short* gsA = xb + (row0 + w * 32 + (l >> 3)) * 512 + swz;
  const unsigned short* gsB = Mb + bb * 262144 + (col0 + w * 32 + (l >> 3)) * 512 + swz;

  f32x4 acc[4][4] = {};
  stage_tile(gsA, gsB, As[0], Bs[0], w);
  __syncthreads();
  for (int kt = 0; kt < 7; ++kt) {
    stage_tile(gsA + (kt + 1) * 64, gsB + (kt + 1) * 64,
               As[(kt + 1) & 1], Bs[(kt + 1) & 1], w);
    compute_tile(As[kt & 1], Bs[kt & 1], wr, wc, g, c16, acc);
    __syncthreads();
  }
  compute_tile(As[1], Bs[1], wr, wc, g, c16, acc);

  float bo[4];
#pragma unroll
  for (int ni = 0; ni < 4; ++ni)
    bo[ni] = bout[col0 + wc * 64 + ni * 16 + c16];
#pragma unroll
  for (int mi = 0; mi < 4; ++mi)
#pragma unroll
    for (int ni = 0; ni < 4; ++ni) {
      const int colg = col0 + wc * 64 + ni * 16 + c16;
#pragma unroll
      for (int r = 0; r < 4; ++r) {
        const int rowg = row0 + wr * 64 + mi * 16 + g * 4 + r;
        y[rowg * 512 + colg] = acc[mi][ni][r] + bo[ni];
      }
    }
}

// ---------------------------------------------------------------------------
extern "C" void kernel_launch(void* const* d_in, const int* in_sizes, int n_in,
                              void* d_out, int out_size, void* d_ws, size_t ws_size,
                              hipStream_t stream) {
  (void)in_sizes; (void)n_in; (void)out_size; (void)ws_size;
  const float* x    = (const float*)d_in[0];
  const float* Wqkv = (const float*)d_in[1];
  const float* gK   = (const float*)d_in[2];
  const float* bK   = (const float*)d_in[3];
  const float* gV   = (const float*)d_in[4];
  const float* bV   = (const float*)d_in[5];
  const float* Wout = (const float*)d_in[6];
  const float* bout = (const float*)d_in[7];
  float* y = (float*)d_out;

  // workspace carve (~40 MB)
  char* w = (char*)d_ws;
  unsigned short* xb  = (unsigned short*)(w);              // 33,554,432
  unsigned short* Wb  = (unsigned short*)(w + 33554432);   //  1,572,864
  unsigned short* Wob = (unsigned short*)(w + 35127296);   //    524,288
  float*          P   = (float*)         (w + 35651584);   //    524,288
  unsigned short* Gt  = (unsigned short*)(w + 36175872);   //  2,097,152
  unsigned short* Mb  = (unsigned short*)(w + 38273024);   //  2,097,152

  k_cvt_bf16<<<16384, 256, 0, stream>>>(x, xb, 4194304);
  k_cvt_bf16<<<768, 256, 0, stream>>>(Wqkv, Wb, 196608);
  k_cvt_bf16<<<256, 256, 0, stream>>>(Wout, Wob, 65536);
  hipMemsetAsync(P, 0, 524288, stream);

  k1_kvp<<<dim3(256, 8), 256, 0, stream>>>(xb, Wb, gK, bK, gV, bV, P);
  k3a_g<<<dim3(32, 8), 256, 0, stream>>>(Wqkv, P, Gt);
  k3b_m<<<dim3(4, 4, 4), 256, 0, stream>>>(Wob, Gt, Mb);
  k4_final<<<dim3(256, 4), 256, 0, stream>>>(xb, Mb, bout, y);
}